// Round 7
// baseline (362.005 us; speedup 1.0000x reference)
//
#include <hip/hip_runtime.h>

#define N_NODES 100000
#define N_EDGES 1600000
#define D_FEAT  128

#define SCAN_CHUNK 1024
#define N_CHUNKS   ((N_NODES + SCAN_CHUNK - 1) / SCAN_CHUNK)   // 98

// ===========================================================================
// CSR path (primary): histogram -> scan -> bucket scatter -> pull aggregate
// ===========================================================================

// ---- 0) zero deg + cursor arrays -----------------------------------------
__global__ void zero_ints(int* __restrict__ deg, int* __restrict__ cnt) {
    size_t tid    = (size_t)blockIdx.x * blockDim.x + threadIdx.x;
    size_t stride = (size_t)gridDim.x * blockDim.x;
    for (size_t i = tid; i < N_NODES; i += stride) { deg[i] = 0; cnt[i] = 0; }
}

// ---- 1) in-degree histogram (int atomics; deg is 400KB -> L2-resident) ----
__global__ void histogram(const int* __restrict__ dst, int* __restrict__ deg) {
    const size_t total4 = N_EDGES / 4;                    // 400000
    size_t tid    = (size_t)blockIdx.x * blockDim.x + threadIdx.x;
    size_t stride = (size_t)gridDim.x * blockDim.x;
    for (size_t i = tid; i < total4; i += stride) {
        int4 d4 = reinterpret_cast<const int4*>(dst)[i];
        atomicAdd(&deg[d4.x], 1);
        atomicAdd(&deg[d4.y], 1);
        atomicAdd(&deg[d4.z], 1);
        atomicAdd(&deg[d4.w], 1);
    }
}

// ---- 2a) per-chunk exclusive scan (chunk = 1024 = 256 thr x 4) ------------
__global__ void scan_chunks(const int* __restrict__ deg,
                            int* __restrict__ offs,
                            int* __restrict__ bsums) {
    __shared__ int lds[256];
    const int b = blockIdx.x, t = threadIdx.x;
    const int base = b * SCAN_CHUNK + t * 4;
    int v0 = (base + 0 < N_NODES) ? deg[base + 0] : 0;
    int v1 = (base + 1 < N_NODES) ? deg[base + 1] : 0;
    int v2 = (base + 2 < N_NODES) ? deg[base + 2] : 0;
    int v3 = (base + 3 < N_NODES) ? deg[base + 3] : 0;
    const int s = v0 + v1 + v2 + v3;
    lds[t] = s;
    __syncthreads();
    int x = s;
    for (int off = 1; off < 256; off <<= 1) {
        int y = (t >= off) ? lds[t - off] : 0;
        __syncthreads();
        x += y;
        lds[t] = x;
        __syncthreads();
    }
    if (t == 255) bsums[b] = x;          // chunk total
    int excl = x - s;                    // exclusive prefix within chunk
    if (base + 0 < N_NODES) offs[base + 0] = excl;  excl += v0;
    if (base + 1 < N_NODES) offs[base + 1] = excl;  excl += v1;
    if (base + 2 < N_NODES) offs[base + 2] = excl;  excl += v2;
    if (base + 3 < N_NODES) offs[base + 3] = excl;
}

// ---- 2b) exclusive scan of the 98 chunk sums (single block) ---------------
__global__ void scan_bsums(int* __restrict__ bsums) {
    __shared__ int lds[128];
    const int t = threadIdx.x;           // 128 threads
    int v = (t < N_CHUNKS) ? bsums[t] : 0;
    lds[t] = v;
    __syncthreads();
    int x = v;
    for (int off = 1; off < 128; off <<= 1) {
        int y = (t >= off) ? lds[t - off] : 0;
        __syncthreads();
        x += y;
        lds[t] = x;
        __syncthreads();
    }
    if (t < N_CHUNKS) bsums[t] = x - v;  // exclusive
}

// ---- 3) bucket-scatter src ids into per-dst edge lists --------------------
__global__ void build_lists(const int* __restrict__ src,
                            const int* __restrict__ dst,
                            const int* __restrict__ offs,
                            const int* __restrict__ bsums,
                            int* __restrict__ cnt,
                            int* __restrict__ edge_list) {
    const size_t total4 = N_EDGES / 4;                    // 400000
    size_t tid    = (size_t)blockIdx.x * blockDim.x + threadIdx.x;
    size_t stride = (size_t)gridDim.x * blockDim.x;
    for (size_t i = tid; i < total4; i += stride) {
        int4 d4 = reinterpret_cast<const int4*>(dst)[i];
        int4 s4 = reinterpret_cast<const int4*>(src)[i];
        {
            const int d = d4.x;
            const int pos = offs[d] + bsums[d >> 10] + atomicAdd(&cnt[d], 1);
            edge_list[pos] = s4.x;
        }
        {
            const int d = d4.y;
            const int pos = offs[d] + bsums[d >> 10] + atomicAdd(&cnt[d], 1);
            edge_list[pos] = s4.y;
        }
        {
            const int d = d4.z;
            const int pos = offs[d] + bsums[d >> 10] + atomicAdd(&cnt[d], 1);
            edge_list[pos] = s4.z;
        }
        {
            const int d = d4.w;
            const int pos = offs[d] + bsums[d >> 10] + atomicAdd(&cnt[d], 1);
            edge_list[pos] = s4.w;
        }
    }
}

// ---- 4) pull aggregation: half-wave (32 lanes) per node, float4 per lane --
__global__ void __launch_bounds__(256)
aggregate(const float* __restrict__ feat,
          const int*   __restrict__ edge_list,
          const int*   __restrict__ offs,
          const int*   __restrict__ bsums,
          const int*   __restrict__ deg,
          float*       __restrict__ out) {
    const size_t gtid = (size_t)blockIdx.x * blockDim.x + threadIdx.x;
    const int node = (int)(gtid >> 5);
    const int lane = threadIdx.x & 31;
    if (node >= N_NODES) return;

    const int base = offs[node] + bsums[node >> 10];
    const int d    = deg[node];
    const size_t col = (size_t)lane * 4;

    float4 acc0 = make_float4(0.f, 0.f, 0.f, 0.f);
    float4 acc1 = make_float4(0.f, 0.f, 0.f, 0.f);

    int j = 0;
    for (; j + 1 < d; j += 2) {
        const int s0 = edge_list[base + j];
        const int s1 = edge_list[base + j + 1];
        float4 a = *reinterpret_cast<const float4*>(feat + (size_t)s0 * D_FEAT + col);
        float4 b = *reinterpret_cast<const float4*>(feat + (size_t)s1 * D_FEAT + col);
        acc0.x += a.x; acc0.y += a.y; acc0.z += a.z; acc0.w += a.w;
        acc1.x += b.x; acc1.y += b.y; acc1.z += b.z; acc1.w += b.w;
    }
    if (j < d) {
        const int s0 = edge_list[base + j];
        float4 a = *reinterpret_cast<const float4*>(feat + (size_t)s0 * D_FEAT + col);
        acc0.x += a.x; acc0.y += a.y; acc0.z += a.z; acc0.w += a.w;
    }
    const float inv = 1.0f / (float)max(d, 1);
    float4 r;
    r.x = (acc0.x + acc1.x) * inv;
    r.y = (acc0.y + acc1.y) * inv;
    r.z = (acc0.z + acc1.z) * inv;
    r.w = (acc0.w + acc1.w) * inv;
    *reinterpret_cast<float4*>(out + (size_t)node * D_FEAT + col) = r;
}

// ===========================================================================
// Fallback path (atomic scatter) — only if ws_size is too small for CSR
// ===========================================================================
__global__ void zero_out_deg(float* __restrict__ out, float* __restrict__ deg) {
    const size_t total4 = (size_t)N_NODES * D_FEAT / 4;
    size_t tid    = (size_t)blockIdx.x * blockDim.x + threadIdx.x;
    size_t stride = (size_t)gridDim.x * blockDim.x;
    float4 z = make_float4(0.f, 0.f, 0.f, 0.f);
    for (size_t i = tid; i < total4; i += stride)
        reinterpret_cast<float4*>(out)[i] = z;
    for (size_t i = tid; i < N_NODES; i += stride)
        deg[i] = 0.f;
}

__global__ void scatter_atomic(const float* __restrict__ feat,
                               const int*   __restrict__ src,
                               const int*   __restrict__ dst,
                               float*       __restrict__ out,
                               float*       __restrict__ deg) {
    const size_t total  = (size_t)N_EDGES * 32;
    size_t tid    = (size_t)blockIdx.x * blockDim.x + threadIdx.x;
    size_t stride = (size_t)gridDim.x * blockDim.x;
    for (size_t i = tid; i < total; i += stride) {
        const int e = (int)(i >> 5);
        const int c = (int)(i & 31);
        const int s = src[e];
        const int d = dst[e];
        float4 v = reinterpret_cast<const float4*>(feat + (size_t)s * D_FEAT)[c];
        float* o = out + (size_t)d * D_FEAT + (size_t)c * 4;
        unsafeAtomicAdd(o + 0, v.x);
        unsafeAtomicAdd(o + 1, v.y);
        unsafeAtomicAdd(o + 2, v.z);
        unsafeAtomicAdd(o + 3, v.w);
        if (c == 0) unsafeAtomicAdd(deg + d, 1.0f);
    }
}

__global__ void div_mean(float* __restrict__ out, const float* __restrict__ deg) {
    const size_t total4 = (size_t)N_NODES * D_FEAT / 4;
    size_t tid    = (size_t)blockIdx.x * blockDim.x + threadIdx.x;
    size_t stride = (size_t)gridDim.x * blockDim.x;
    for (size_t i = tid; i < total4; i += stride) {
        const float inv = 1.0f / fmaxf(deg[i >> 5], 1.0f);
        float4 v = reinterpret_cast<float4*>(out)[i];
        v.x *= inv; v.y *= inv; v.z *= inv; v.w *= inv;
        reinterpret_cast<float4*>(out)[i] = v;
    }
}

// ===========================================================================
extern "C" void kernel_launch(void* const* d_in, const int* in_sizes, int n_in,
                              void* d_out, int out_size, void* d_ws, size_t ws_size,
                              hipStream_t stream) {
    const float* feat = (const float*)d_in[0];
    const int*   src  = (const int*)d_in[1];
    const int*   dst  = (const int*)d_in[2];
    float* out = (float*)d_out;

    // CSR workspace (ints): deg[N] | cnt[N] | offs[N] | bsums[128] | edge_list[E]
    const size_t need = ((size_t)3 * N_NODES + 128 + N_EDGES) * sizeof(int);

    if (ws_size >= need) {
        int* deg       = (int*)d_ws;
        int* cnt       = deg  + N_NODES;
        int* offs      = cnt  + N_NODES;
        int* bsums     = offs + N_NODES;
        int* edge_list = bsums + 128;

        zero_ints   <<<512,      256, 0, stream>>>(deg, cnt);
        histogram   <<<1024,     256, 0, stream>>>(dst, deg);
        scan_chunks <<<N_CHUNKS, 256, 0, stream>>>(deg, offs, bsums);
        scan_bsums  <<<1,        128, 0, stream>>>(bsums);
        build_lists <<<1024,     256, 0, stream>>>(src, dst, offs, bsums, cnt, edge_list);
        // 100000 nodes x 32 threads = 3.2M threads -> 12500 blocks of 256
        aggregate   <<<12500,    256, 0, stream>>>(feat, edge_list, offs, bsums, deg, out);
    } else {
        float* fdeg = (float*)d_ws;
        zero_out_deg  <<<2048, 256, 0, stream>>>(out, fdeg);
        scatter_atomic<<<8192, 256, 0, stream>>>(feat, src, dst, out, fdeg);
        div_mean      <<<2048, 256, 0, stream>>>(out, fdeg);
    }
}